// Round 2
// baseline (13713.403 us; speedup 1.0000x reference)
//
#include <hip/hip_runtime.h>
#include <hip/hip_bf16.h>

// Problem dims
constexpr int Bb = 256, Tt = 128, Ff = 256, Hh = 512;
constexpr int TF = Tt * Ff;                       // 32768
constexpr long OFF_RECON = (long)Bb * Tt * Ff;    // 8388608
constexpr long OFF_H     = 2L * Bb * Tt * Ff;     // 16777216
constexpr long OFF_LOSS  = OFF_H + (long)Bb * Hh; // 16908288

__device__ inline float sigf(float v){ return 1.f / (1.f + expf(-v)); }

struct EpArgs {
  const float *b1, *b2;
  float *h, *xh, *xr, *xu, *Arnn, *gates;
  const float *x, *mask, *Wfr;
  float *o_ximp, *o_recon;
  float *num, *den;
  int t;
};

enum { EP_DECAY, EP_XH, EP_XU, EP_BETA, EP_GATES };

// C[m,n] = epilogue( sum_k A[m,k] * W[n,k] ), A row-major (lda), W row-major [N,K].
// 32x32 tile, 256 threads, 2x2 micro-tile per thread, fp32 accumulate.
template<int MODE, bool TWO>
__global__ __launch_bounds__(256) void gemm_nt(
    const float* __restrict__ A1, int lda1, const float* __restrict__ W1, int K1,
    const float* __restrict__ A2, int lda2, const float* __restrict__ W2, int K2,
    EpArgs e)
{
  constexpr int BM = 32, BN = 32, BK = 32;
  __shared__ float As[BK][BM + 4];
  __shared__ float Bs[BK][BN + 4];
  const int tid = threadIdx.x;
  const int m0 = blockIdx.y * BM, n0 = blockIdx.x * BN;
  const int tx = tid & 15, ty = tid >> 4;
  const int r  = tid >> 3;          // 0..31 (row within tile)
  const int cb = (tid & 7) << 2;    // 0,4,..,28 (k base)

  float a00 = 0.f, a01 = 0.f, a10 = 0.f, a11 = 0.f;

  for (int k0 = 0; k0 < K1; k0 += BK) {
    const float* ap = A1 + (size_t)(m0 + r) * lda1 + k0 + cb;
    const float* wp = W1 + (size_t)(n0 + r) * K1 + k0 + cb;
    #pragma unroll
    for (int c2 = 0; c2 < 4; ++c2) As[cb + c2][r] = ap[c2];
    #pragma unroll
    for (int c2 = 0; c2 < 4; ++c2) Bs[cb + c2][r] = wp[c2];
    __syncthreads();
    #pragma unroll
    for (int k = 0; k < BK; ++k) {
      float x0 = As[k][ty * 2], x1 = As[k][ty * 2 + 1];
      float w0 = Bs[k][tx * 2], w1 = Bs[k][tx * 2 + 1];
      a00 += x0 * w0; a01 += x0 * w1; a10 += x1 * w0; a11 += x1 * w1;
    }
    __syncthreads();
  }
  if constexpr (TWO) {
    for (int k0 = 0; k0 < K2; k0 += BK) {
      const float* ap = A2 + (size_t)(m0 + r) * lda2 + k0 + cb;
      const float* wp = W2 + (size_t)(n0 + r) * K2 + k0 + cb;
      #pragma unroll
      for (int c2 = 0; c2 < 4; ++c2) As[cb + c2][r] = ap[c2];
      #pragma unroll
      for (int c2 = 0; c2 < 4; ++c2) Bs[cb + c2][r] = wp[c2];
      __syncthreads();
      #pragma unroll
      for (int k = 0; k < BK; ++k) {
        float x0 = As[k][ty * 2], x1 = As[k][ty * 2 + 1];
        float w0 = Bs[k][tx * 2], w1 = Bs[k][tx * 2 + 1];
        a00 += x0 * w0; a01 += x0 * w1; a10 += x1 * w0; a11 += x1 * w1;
      }
      __syncthreads();
    }
  }

  const float acc[2][2] = {{a00, a01}, {a10, a11}};
  float lnum = 0.f, lden = 0.f;
  #pragma unroll
  for (int i = 0; i < 2; ++i) {
    const int m = m0 + ty * 2 + i;
    #pragma unroll
    for (int j = 0; j < 2; ++j) {
      const int n = n0 + tx * 2 + j;
      const float a = acc[i][j];
      if constexpr (MODE == EP_DECAY) {
        float v = a + e.b1[n];                      // d@W_gh^T + b_gh
        e.h[m * Hh + n] *= expf(-fmaxf(v, 0.f));    // h *= gamma_h
      } else if constexpr (MODE == EP_XH) {
        float v = a + e.b1[n];                      // x_h
        e.xh[m * Ff + n] = v;
        size_t gi = (size_t)m * TF + (size_t)e.t * Ff + n;
        float mm = e.mask[gi], xx = e.x[gi];
        e.xr[m * Ff + n] = mm * xx + (1.f - mm) * v;
      } else if constexpr (MODE == EP_XU) {
        float xrv = e.xr[m * Ff + n];
        float wd  = e.Wfr[(size_t)n * Ff + n];      // zero-diagonal correction
        e.xu[m * Ff + n] = a + e.b1[n] - xrv * wd;
      } else if constexpr (MODE == EP_BETA) {
        float bet = sigf(a + e.b1[n]);
        float xc  = bet * e.xu[m * Ff + n] + (1.f - bet) * e.xh[m * Ff + n];
        size_t gi = (size_t)m * TF + (size_t)e.t * Ff + n;
        float mm = e.mask[gi], xx = e.x[gi];
        e.o_recon[gi] = xc;
        float xi = mm * xx + (1.f - mm) * xc;
        e.o_ximp[gi] = xi;
        e.Arnn[m * (2 * Ff) + n] = xi;              // first half of rnn_in
        lnum += fabsf(xc - xx) * mm;
        lden += mm;
      } else if constexpr (MODE == EP_GATES) {
        e.gates[(size_t)m * (4 * Hh) + n] = a + e.b1[n] + e.b2[n];
      }
    }
  }
  if constexpr (MODE == EP_BETA) {
    #pragma unroll
    for (int o = 32; o; o >>= 1) { lnum += __shfl_down(lnum, o); lden += __shfl_down(lden, o); }
    if ((tid & 63) == 0) { atomicAdd(e.num + e.t, lnum); atomicAdd(e.den + e.t, lden); }
  }
}

// Per-step recurrence-independent prep: gamma_x and mask halves of A_beta, mask half of A_rnn.
__global__ __launch_bounds__(256) void k_prep(
    const float* __restrict__ deltas, const float* __restrict__ mask,
    const float* __restrict__ wgx, const float* __restrict__ bgx,
    float* __restrict__ Abeta, float* __restrict__ Arnn, int t)
{
  int idx = blockIdx.x * 256 + threadIdx.x;   // < B*F
  int m = idx >> 8, f = idx & 255;
  size_t gi = (size_t)m * TF + (size_t)t * Ff + f;
  float d  = deltas[gi];
  float gx = expf(-fmaxf(d * wgx[f] + bgx[f], 0.f));
  float mm = mask[gi];
  Abeta[m * 512 + f]       = gx;
  Abeta[m * 512 + 256 + f] = mm;
  Arnn [m * 512 + 256 + f] = mm;
}

__global__ __launch_bounds__(256) void k_lstm(
    const float* __restrict__ gates, float* __restrict__ c, float* __restrict__ h)
{
  int idx = blockIdx.x * 256 + threadIdx.x;   // < B*H
  int m = idx >> 9, n = idx & 511;
  const float* g = gates + (size_t)m * 2048;
  float ig = sigf(g[n]);
  float fg = sigf(g[512 + n]);
  float gg = tanhf(g[1024 + n]);
  float og = sigf(g[1536 + n]);
  float cv = fg * c[idx] + ig * gg;
  c[idx] = cv;
  h[idx] = og * tanhf(cv);
}

__global__ __launch_bounds__(256) void k_final(
    const float* __restrict__ h, const float* __restrict__ num,
    const float* __restrict__ den, float* __restrict__ out)
{
  int idx = blockIdx.x * 256 + threadIdx.x;
  if (idx < Bb * Hh) out[OFF_H + idx] = h[idx];
  if (blockIdx.x == 0 && threadIdx.x < 64) {
    int t = threadIdx.x;
    float s = num[t] / (den[t] + 1e-12f) + num[t + 64] / (den[t + 64] + 1e-12f);
    #pragma unroll
    for (int o = 32; o; o >>= 1) s += __shfl_down(s, o);
    if (t == 0) { out[OFF_LOSS] = s; out[OFF_LOSS + 1] = 0.f; }
  }
}

extern "C" void kernel_launch(void* const* d_in, const int* in_sizes, int n_in,
                              void* d_out, int out_size, void* d_ws, size_t ws_size,
                              hipStream_t stream)
{
  const float* x      = (const float*)d_in[0];
  const float* mask   = (const float*)d_in[1];
  const float* deltas = (const float*)d_in[2];
  const float* W_gh   = (const float*)d_in[3];
  const float* b_gh   = (const float*)d_in[4];
  const float* w_gx   = (const float*)d_in[5];
  const float* b_gx   = (const float*)d_in[6];
  const float* W_hist = (const float*)d_in[7];
  const float* b_hist = (const float*)d_in[8];
  const float* W_fr   = (const float*)d_in[9];
  const float* b_fr   = (const float*)d_in[10];
  const float* W_comb = (const float*)d_in[11];
  const float* b_comb = (const float*)d_in[12];
  const float* W_ih   = (const float*)d_in[13];
  const float* b_ih   = (const float*)d_in[14];
  const float* W_hh   = (const float*)d_in[15];
  const float* b_hh   = (const float*)d_in[16];
  float* out = (float*)d_out;

  float* ws    = (float*)d_ws;
  float* h     = ws;                 // 131072
  float* c     = ws + 131072;        // 131072
  float* num   = ws + 262144;        // 128
  float* den   = ws + 262272;        // 128
  float* xh    = ws + 262400;        // 65536
  float* xr    = ws + 327936;        // 65536
  float* xu    = ws + 393472;        // 65536
  float* Abeta = ws + 459008;        // 131072
  float* Arnn  = ws + 590080;        // 131072
  float* gates = ws + 721152;        // 524288

  // zero h, c, num, den (re-done on every graph replay)
  hipMemsetAsync(d_ws, 0, 262400 * sizeof(float), stream);

  EpArgs e{};
  e.h = h; e.xh = xh; e.xr = xr; e.xu = xu; e.Arnn = Arnn; e.gates = gates;
  e.x = x; e.mask = mask; e.Wfr = W_fr;
  e.o_ximp = out; e.o_recon = out + OFF_RECON;
  e.num = num; e.den = den;

  dim3 blk(256);
  for (int t = 0; t < Tt; ++t) {
    e.t = t;
    k_prep<<<dim3(Bb * Ff / 256), blk, 0, stream>>>(deltas, mask, w_gx, b_gx, Abeta, Arnn, t);

    EpArgs e1 = e; e1.b1 = b_gh;   // h *= exp(-relu(d_t @ W_gh^T + b_gh))
    gemm_nt<EP_DECAY, false><<<dim3(Hh / 32, Bb / 32), blk, 0, stream>>>(
        deltas + (size_t)t * Ff, TF, W_gh, Ff, nullptr, 0, nullptr, 0, e1);

    EpArgs e2 = e; e2.b1 = b_hist; // x_h = h @ W_hist^T + b_hist ; x_r
    gemm_nt<EP_XH, false><<<dim3(Ff / 32, Bb / 32), blk, 0, stream>>>(
        h, Hh, W_hist, Hh, nullptr, 0, nullptr, 0, e2);

    EpArgs e3 = e; e3.b1 = b_fr;   // xu = x_r @ (W_fr masked)^T + b_fr
    gemm_nt<EP_XU, false><<<dim3(Ff / 32, Bb / 32), blk, 0, stream>>>(
        xr, Ff, W_fr, Ff, nullptr, 0, nullptr, 0, e3);

    EpArgs e4 = e; e4.b1 = b_comb; // beta, x_comb, outputs, loss partials
    gemm_nt<EP_BETA, false><<<dim3(Ff / 32, Bb / 32), blk, 0, stream>>>(
        Abeta, 2 * Ff, W_comb, 2 * Ff, nullptr, 0, nullptr, 0, e4);

    EpArgs e5 = e; e5.b1 = b_ih; e5.b2 = b_hh; // gates = rnn_in@W_ih^T + h@W_hh^T + b
    gemm_nt<EP_GATES, true><<<dim3(4 * Hh / 32, Bb / 32), blk, 0, stream>>>(
        Arnn, 2 * Ff, W_ih, 2 * Ff, h, Hh, W_hh, Hh, e5);

    k_lstm<<<dim3(Bb * Hh / 256), blk, 0, stream>>>(gates, c, h);
  }
  k_final<<<dim3(Bb * Hh / 256), blk, 0, stream>>>(h, num, den, out);
}

// Round 3
// 6932.929 us; speedup vs baseline: 1.9780x; 1.9780x over previous
//
#include <hip/hip_runtime.h>
#include <hip/hip_bf16.h>

typedef float f32x4 __attribute__((ext_vector_type(4)));
typedef __bf16 bf16x8 __attribute__((ext_vector_type(8)));
typedef short s16x8 __attribute__((ext_vector_type(8)));
typedef unsigned short u16;

constexpr int Bb = 256, Tt = 128, Ff = 256, Hh = 512;
constexpr int TF = Tt * Ff;                       // 32768
constexpr long OFF_RECON = (long)Bb * Tt * Ff;    // 8388608
constexpr long OFF_H     = 2L * Bb * Tt * Ff;     // 16777216
constexpr long OFF_LOSS  = OFF_H + (long)Bb * Hh; // 16908288

__device__ inline float sigf(float v){ return 1.f / (1.f + expf(-v)); }
__device__ inline u16 f2b(float f){
  unsigned u = __float_as_uint(f);
  u += 0x7fffu + ((u >> 16) & 1u);   // RNE
  return (u16)(u >> 16);
}
__device__ inline float b2f(u16 b){ return __uint_as_float(((unsigned)b) << 16); }

__device__ inline f32x4 mfma16(bf16x8 a, bf16x8 b, f32x4 c){
  return __builtin_amdgcn_mfma_f32_16x16x32_bf16(a, b, c, 0, 0, 0);
}
__device__ inline bf16x8 ldb8(const u16* p){ return *reinterpret_cast<const bf16x8*>(p); }
__device__ inline bf16x8 cvt8(const float* p){
  const float4 a = ((const float4*)p)[0], b = ((const float4*)p)[1];
  s16x8 r;
  r[0]=f2b(a.x); r[1]=f2b(a.y); r[2]=f2b(a.z); r[3]=f2b(a.w);
  r[4]=f2b(b.x); r[5]=f2b(b.y); r[6]=f2b(b.z); r[7]=f2b(b.w);
  return __builtin_bit_cast(bf16x8, r);
}

enum { M_GH, M_BETA, M_XH, M_XU, M_GATES };

struct P {
  const float *x, *mask, *deltas;
  const float *b_gh, *w_gx, *b_gx, *b_hist, *b_fr, *b_comb, *b_ih, *b_hh;
  const u16 *Wgh, *Whist, *Wfr, *Wcomb, *Wih, *Whh;
  u16 *gammah, *beta, *hdec_r, *hdec_w, *ximp, *xr;
  float *xh, *c, *num, *den;
  float *out;
  int t;
};

// Wave computes a 32x32 output tile as 2x2 MFMA 16x16x32 fragments; GATES mode
// additionally carries 4 gate groups of accumulators (i,f,g,o) and fuses LSTM.
// Hoisted modes (GH/BETA): 256-thread block = 2x2 waves (64x64 tile).
// Serial modes: 64-thread block = 1 wave (32x32 tile) for max block parallelism.
template<int MODE>
__global__ __launch_bounds__(256) void gk(P p)
{
  constexpr int K  = (MODE==M_GH)?256 : (MODE==M_BETA)?512 : (MODE==M_XH)?512 : (MODE==M_XU)?256 : 1024;
  constexpr int NG = (MODE==M_GATES)?4:1;
  constexpr bool BIG = (MODE==M_GH || MODE==M_BETA);
  const int lane = threadIdx.x & 63;
  const int w = threadIdx.x >> 6;
  int m0, n0;
  if constexpr (BIG) { m0 = blockIdx.y*64 + (w>>1)*32; n0 = blockIdx.x*64 + (w&1)*32; }
  else               { m0 = blockIdx.y*32;             n0 = blockIdx.x*32; }
  const int fr = lane & 15;          // row within fragment (A-row / B-col)
  const int kg = (lane >> 4) << 3;   // lane's k sub-offset (0,8,16,24)
  const int t = p.t;

  f32x4 acc[NG][2][2] = {};

  for (int k = 0; k < K; k += 32) {
    const int kk = k + kg;
    bf16x8 a[2], b[NG][2];
    #pragma unroll
    for (int r = 0; r < 2; ++r) {
      const int mr = m0 + 16*r + fr;
      if constexpr (MODE == M_GH) {
        a[r] = cvt8(p.deltas + (size_t)mr*256 + kk);
      } else if constexpr (MODE == M_BETA) {
        if (kk < 256) {
          const float4 d0 = *(const float4*)(p.deltas + (size_t)mr*256 + kk);
          const float4 d1 = *(const float4*)(p.deltas + (size_t)mr*256 + kk + 4);
          const float4 w0 = *(const float4*)(p.w_gx + kk);
          const float4 w1 = *(const float4*)(p.w_gx + kk + 4);
          const float4 g0 = *(const float4*)(p.b_gx + kk);
          const float4 g1 = *(const float4*)(p.b_gx + kk + 4);
          s16x8 v;
          v[0]=f2b(expf(-fmaxf(d0.x*w0.x+g0.x,0.f)));
          v[1]=f2b(expf(-fmaxf(d0.y*w0.y+g0.y,0.f)));
          v[2]=f2b(expf(-fmaxf(d0.z*w0.z+g0.z,0.f)));
          v[3]=f2b(expf(-fmaxf(d0.w*w0.w+g0.w,0.f)));
          v[4]=f2b(expf(-fmaxf(d1.x*w1.x+g1.x,0.f)));
          v[5]=f2b(expf(-fmaxf(d1.y*w1.y+g1.y,0.f)));
          v[6]=f2b(expf(-fmaxf(d1.z*w1.z+g1.z,0.f)));
          v[7]=f2b(expf(-fmaxf(d1.w*w1.w+g1.w,0.f)));
          a[r] = __builtin_bit_cast(bf16x8, v);
        } else {
          a[r] = cvt8(p.mask + (size_t)mr*256 + (kk-256));
        }
      } else if constexpr (MODE == M_XH) {
        a[r] = ldb8(p.hdec_r + (size_t)mr*512 + kk);
      } else if constexpr (MODE == M_XU) {
        a[r] = ldb8(p.xr + (size_t)mr*256 + kk);
      } else { // GATES: A = [x_imp(256) | mask_t(256) | h_dec(512)]
        if (kk < 256)      a[r] = ldb8(p.ximp + (size_t)mr*256 + kk);
        else if (kk < 512) a[r] = cvt8(p.mask + (size_t)mr*TF + (size_t)t*256 + (kk-256));
        else               a[r] = ldb8(p.hdec_r + (size_t)mr*512 + (kk-512));
      }
    }
    #pragma unroll
    for (int g = 0; g < NG; ++g) {
      #pragma unroll
      for (int cc = 0; cc < 2; ++cc) {
        const int nr = n0 + 16*cc + fr;
        if constexpr (MODE == M_GH)        b[g][cc] = ldb8(p.Wgh   + (size_t)nr*256 + kk);
        else if constexpr (MODE == M_BETA) b[g][cc] = ldb8(p.Wcomb + (size_t)nr*512 + kk);
        else if constexpr (MODE == M_XH)   b[g][cc] = ldb8(p.Whist + (size_t)nr*512 + kk);
        else if constexpr (MODE == M_XU)   b[g][cc] = ldb8(p.Wfr   + (size_t)nr*256 + kk);
        else b[g][cc] = (kk < 512) ? ldb8(p.Wih + (size_t)(g*512 + nr)*512 + kk)
                                   : ldb8(p.Whh + (size_t)(g*512 + nr)*512 + (kk-512));
      }
    }
    #pragma unroll
    for (int g = 0; g < NG; ++g)
      #pragma unroll
      for (int r = 0; r < 2; ++r)
        #pragma unroll
        for (int cc = 0; cc < 2; ++cc)
          acc[g][r][cc] = mfma16(a[r], b[g][cc], acc[g][r][cc]);
  }

  float lnum = 0.f;
  #pragma unroll
  for (int r = 0; r < 2; ++r) {
    #pragma unroll
    for (int cc = 0; cc < 2; ++cc) {
      #pragma unroll
      for (int q = 0; q < 4; ++q) {
        const int m = m0 + 16*r + (lane>>4)*4 + q;
        const int n = n0 + 16*cc + (lane&15);
        if constexpr (MODE == M_GH) {
          float v = expf(-fmaxf(acc[0][r][cc][q] + p.b_gh[n], 0.f));
          p.gammah[(size_t)m*512 + n] = f2b(v);
        } else if constexpr (MODE == M_BETA) {
          float v = sigf(acc[0][r][cc][q] + p.b_comb[n]);
          p.beta[(size_t)m*256 + n] = f2b(v);
        } else if constexpr (MODE == M_XH) {
          float v = acc[0][r][cc][q] + p.b_hist[n];
          p.xh[m*256 + n] = v;
          size_t gi = (size_t)m*TF + (size_t)t*256 + n;
          float mm = p.mask[gi];
          p.xr[m*256 + n] = f2b(mm*p.x[gi] + (1.f-mm)*v);
        } else if constexpr (MODE == M_XU) {
          float xu = acc[0][r][cc][q] + p.b_fr[n];
          float bet = b2f(p.beta[((size_t)m*128 + t)*256 + n]);
          float xhv = p.xh[m*256 + n];
          float xc  = bet*xu + (1.f-bet)*xhv;
          size_t gi = (size_t)m*TF + (size_t)t*256 + n;
          float mm = p.mask[gi], xx = p.x[gi];
          p.out[OFF_RECON + gi] = xc;
          float xi = mm*xx + (1.f-mm)*xc;
          p.out[gi] = xi;
          p.ximp[m*256 + n] = f2b(xi);
          lnum += fabsf(xc - xx)*mm;
        } else { // GATES + fused LSTM
          float pre[4];
          #pragma unroll
          for (int g = 0; g < 4; ++g)
            pre[g] = acc[g][r][cc][q] + p.b_ih[g*512 + n] + p.b_hh[g*512 + n];
          float ig = sigf(pre[0]), fg = sigf(pre[1]);
          float gg = tanhf(pre[2]), og = sigf(pre[3]);
          const int idx = m*512 + n;
          float cv = fg*p.c[idx] + ig*gg;
          p.c[idx] = cv;
          float hv = og*tanhf(cv);
          if (t == 127) {
            p.out[OFF_H + idx] = hv;
            p.hdec_w[idx] = f2b(hv);
          } else {
            float gn = b2f(p.gammah[((size_t)m*128 + (t+1))*512 + n]);
            p.hdec_w[idx] = f2b(hv*gn);     // pre-decayed h for next step
          }
        }
      }
    }
  }
  if constexpr (MODE == M_XU) {
    #pragma unroll
    for (int o = 32; o; o >>= 1) lnum += __shfl_down(lnum, o);
    if (lane == 0) atomicAdd(p.num + t, lnum);
  }
}

constexpr int CV_TOT = 131072+131072+65536+131072+1048576+1048576; // 2554944
__global__ __launch_bounds__(256) void k_conv(
    const float* Wgh, const float* Whist, const float* Wfr, const float* Wcomb,
    const float* Wih, const float* Whh,
    u16* ogh, u16* ohist, u16* ofr, u16* ocomb, u16* oih, u16* ohh)
{
  int i = blockIdx.x*256 + threadIdx.x;
  if (i >= CV_TOT) return;
  int j = i;
  if (j < 131072) { ogh[j] = f2b(Wgh[j]); return; }       j -= 131072;
  if (j < 131072) { ohist[j] = f2b(Whist[j]); return; }   j -= 131072;
  if (j < 65536)  { ofr[j] = ((j>>8)==(j&255)) ? (u16)0 : f2b(Wfr[j]); return; } j -= 65536;
  if (j < 131072) { ocomb[j] = f2b(Wcomb[j]); return; }   j -= 131072;
  if (j < 1048576){ oih[j] = f2b(Wih[j]); return; }       j -= 1048576;
  ohh[j] = f2b(Whh[j]);
}

__global__ __launch_bounds__(256) void k_den(const float* __restrict__ mask, float* den)
{
  const int t = blockIdx.x;
  float s = 0.f;
  for (int b = 0; b < Bb; ++b)
    s += mask[(size_t)b*TF + (size_t)t*256 + threadIdx.x];
  __shared__ float red[4];
  #pragma unroll
  for (int o = 32; o; o >>= 1) s += __shfl_down(s, o);
  if ((threadIdx.x & 63) == 0) red[threadIdx.x >> 6] = s;
  __syncthreads();
  if (threadIdx.x == 0) den[t] = red[0]+red[1]+red[2]+red[3];
}

__global__ void k_final(const float* num, const float* den, float* out)
{
  if (threadIdx.x < 64) {
    int t = threadIdx.x;
    float s = num[t]/(den[t]+1e-12f) + num[t+64]/(den[t+64]+1e-12f);
    #pragma unroll
    for (int o = 32; o; o >>= 1) s += __shfl_down(s, o);
    if (t == 0) { out[OFF_LOSS] = s; out[OFF_LOSS+1] = 0.f; }
  }
}

extern "C" void kernel_launch(void* const* d_in, const int* in_sizes, int n_in,
                              void* d_out, int out_size, void* d_ws, size_t ws_size,
                              hipStream_t stream)
{
  char* wsb = (char*)d_ws;
  // ws layout (bytes)
  u16*  hdec0  = (u16*)(wsb + 0);          //   262144
  u16*  hdec1  = (u16*)(wsb + 262144);     //   262144
  float* c     = (float*)(wsb + 524288);   //   524288
  float* num   = (float*)(wsb + 1048576);  //      512
  float* den   = (float*)(wsb + 1049088);  //      512
  float* xh    = (float*)(wsb + 1049600);  //   262144
  u16*  xr     = (u16*)(wsb + 1311744);    //   131072
  u16*  ximp   = (u16*)(wsb + 1442816);    //   131072
  u16*  gammah = (u16*)(wsb + 1573888);    // 33554432
  u16*  beta   = (u16*)(wsb + 35128320);   // 16777216
  u16*  Wgh    = (u16*)(wsb + 51905536);   //   262144
  u16*  Whist  = (u16*)(wsb + 52167680);   //   262144
  u16*  Wfr    = (u16*)(wsb + 52429824);   //   131072
  u16*  Wcomb  = (u16*)(wsb + 52560896);   //   262144
  u16*  Wih    = (u16*)(wsb + 52823040);   //  2097152
  u16*  Whh    = (u16*)(wsb + 54920192);   //  2097152  -> total 57017344 B

  P p{};
  p.x = (const float*)d_in[0];  p.mask = (const float*)d_in[1];
  p.deltas = (const float*)d_in[2];
  p.b_gh = (const float*)d_in[4];  p.w_gx = (const float*)d_in[5];
  p.b_gx = (const float*)d_in[6];  p.b_hist = (const float*)d_in[8];
  p.b_fr = (const float*)d_in[10]; p.b_comb = (const float*)d_in[12];
  p.b_ih = (const float*)d_in[14]; p.b_hh = (const float*)d_in[16];
  p.Wgh = Wgh; p.Whist = Whist; p.Wfr = Wfr; p.Wcomb = Wcomb; p.Wih = Wih; p.Whh = Whh;
  p.gammah = gammah; p.beta = beta; p.ximp = ximp; p.xr = xr;
  p.xh = xh; p.c = c; p.num = num; p.den = den;
  p.out = (float*)d_out;

  // zero hdec0, hdec1, c, num each call (graph-replayed)
  hipMemsetAsync(d_ws, 0, 1049088, stream);

  k_conv<<<dim3((CV_TOT+255)/256), dim3(256), 0, stream>>>(
      (const float*)d_in[3], (const float*)d_in[7], (const float*)d_in[9],
      (const float*)d_in[11], (const float*)d_in[13], (const float*)d_in[15],
      Wgh, Whist, Wfr, Wcomb, Wih, Whh);
  k_den<<<dim3(128), dim3(256), 0, stream>>>(p.mask, den);

  gk<M_GH><<<dim3(8, 512), dim3(256), 0, stream>>>(p);    // gamma_h for all t
  gk<M_BETA><<<dim3(4, 512), dim3(256), 0, stream>>>(p);  // beta for all t

  for (int t = 0; t < Tt; ++t) {
    p.t = t;
    p.hdec_r = (t & 1) ? hdec1 : hdec0;
    p.hdec_w = (t & 1) ? hdec0 : hdec1;
    gk<M_XH>   <<<dim3(8, 8),  dim3(64), 0, stream>>>(p);
    gk<M_XU>   <<<dim3(8, 8),  dim3(64), 0, stream>>>(p);
    gk<M_GATES><<<dim3(16, 8), dim3(64), 0, stream>>>(p);
  }
  k_final<<<dim3(1), dim3(64), 0, stream>>>(num, den, p.out);
}